// Round 4
// baseline (274.796 us; speedup 1.0000x reference)
//
#include <hip/hip_runtime.h>

#define NB 2
#define DD 480
#define HH 360
#define WD 32
#define CIN 16
#define COUT 32
#define EPSV 1e-5f
#define NEGS 0.01f

__global__ __launch_bounds__(256) void scatter_grid(const int* __restrict__ coords,
                                                    int* __restrict__ grid, int n) {
    int i = blockIdx.x * 256 + threadIdx.x;
    if (i >= n) return;
    int b = coords[i * 4 + 0];
    int z = coords[i * 4 + 1];
    int y = coords[i * 4 + 2];
    int x = coords[i * 4 + 3];
    grid[(((size_t)b * DD + z) * HH + y) * WD + x] = i;
}

// Compact non-center valid taps per point. Center tap (k=4) is always the
// point itself (grid[coords[i]] == i), handled implicitly by the conv.
// ent entries: (k<<24) | j   (j < 2^24 since n = 200000)
__global__ __launch_bounds__(256) void build_nbr_compact(
    const int* __restrict__ coords, const int* __restrict__ grid,
    int* __restrict__ cnt133, int* __restrict__ ent133,
    int* __restrict__ cnt313, int* __restrict__ ent313, int n) {
    int i = blockIdx.x * 256 + threadIdx.x;
    if (i >= n) return;
    int b = coords[i * 4 + 0];
    int z = coords[i * 4 + 1];
    int y = coords[i * 4 + 2];
    int x = coords[i * 4 + 3];
    size_t base_b = (size_t)b * DD;
    int c1 = 0, c2 = 0;
#pragma unroll
    for (int k = 0; k < 9; ++k) {
        if (k == 4) continue;
        int d0 = k / 3 - 1;  // dy for 133, dz for 313
        int dx = k % 3 - 1;
        int nx = x + dx;
        bool xok = (nx >= 0) && (nx < WD);
        int ny = y + d0;
        if (xok && ny >= 0 && ny < HH) {
            int j = grid[((base_b + z) * HH + ny) * WD + nx];
            if (j >= 0) { ent133[(size_t)c1 * n + i] = (k << 24) | j; ++c1; }
        }
        int nz = z + d0;
        if (xok && nz >= 0 && nz < DD) {
            int j = grid[((base_b + nz) * HH + y) * WD + nx];
            if (j >= 0) { ent313[(size_t)c2 * n + i] = (k << 24) | j; ++c2; }
        }
    }
    cnt133[i] = c1;
    cnt313[i] = c2;
}

// Fold BN scale into weights once per call.
// Ws layout (floats): conv1 [9][16][32] @ 0, conv2 [9][32][32] @ 4608,
//                     conv3 [9][16][32] @ 13824, conv4 [9][32][32] @ 18432
__global__ __launch_bounds__(256) void prep_weights(
    const float* __restrict__ W1, const float* __restrict__ W2,
    const float* __restrict__ W3, const float* __restrict__ W4,
    const float* __restrict__ gamma, const float* __restrict__ beta,
    const float* __restrict__ mean, const float* __restrict__ var,
    float* __restrict__ Ws, float* __restrict__ sh) {
    int t = blockIdx.x * 256 + threadIdx.x;
    if (t < 4 * COUT) {
        float s = gamma[t] * rsqrtf(var[t] + EPSV);
        sh[t] = beta[t] - mean[t] * s;
    }
    if (t >= 27648) return;
    const float* src;
    int loc, bn;
    if (t < 4608)       { src = W1; loc = t;         bn = 0; }
    else if (t < 13824) { src = W2; loc = t - 4608;  bn = 1; }
    else if (t < 18432) { src = W3; loc = t - 13824; bn = 2; }
    else                { src = W4; loc = t - 18432; bn = 3; }
    int co = loc & 31;
    float s = gamma[bn * COUT + co] * rsqrtf(var[bn * COUT + co] + EPSV);
    Ws[t] = src[loc] * s;
}

// Fused pair of independent sparse convs, no LDS:
// center tap uses compile-time-uniform weight indices -> scalar (s_load)
// broadcast from K$; rare extras read weights per-lane from global (L1-hot).
template <int CI>
__global__ __launch_bounds__(256, 5) void conv_pair(
    const float* __restrict__ in0, const int* __restrict__ cnt0,
    const int* __restrict__ ent0, const float* __restrict__ Ws0,
    const float* __restrict__ sh0, float* __restrict__ out0,
    const float* __restrict__ in1, const int* __restrict__ cnt1,
    const int* __restrict__ ent1, const float* __restrict__ Ws1,
    const float* __restrict__ sh1, float* __restrict__ out1,
    int n, int nblk) {
    int tid = threadIdx.x;
    bool second = (int)blockIdx.x >= nblk;
    const float* in  = second ? in1 : in0;
    const int* cnt   = second ? cnt1 : cnt0;
    const int* ent   = second ? ent1 : ent0;
    const float* Ws  = second ? Ws1 : Ws0;
    const float* sh  = second ? sh1 : sh0;
    float* out       = second ? out1 : out0;
    int ib = second ? (int)blockIdx.x - nblk : (int)blockIdx.x;
    int i = ib * 256 + tid;
    if (i >= n) return;

    float acc[COUT];
#pragma unroll
    for (int c = 0; c < COUT; ++c) acc[c] = sh[c];

    // ---- center tap (k=4): weights at compile-time-constant offsets (uniform)
    {
        const float* wc = Ws + 4 * CI * COUT;
        const float4* f4 = (const float4*)(in + (size_t)i * CI);
#pragma unroll
        for (int q = 0; q < CI / 4; ++q) {
            float4 v = f4[q];
#pragma unroll
            for (int e = 0; e < 4; ++e) {
                float fe = (e == 0) ? v.x : (e == 1) ? v.y : (e == 2) ? v.z : v.w;
                const float* wr = wc + (q * 4 + e) * COUT;
#pragma unroll
                for (int c = 0; c < COUT; ++c) acc[c] += fe * wr[c];
            }
        }
    }

    // ---- rare extras (avg ~0.14/point): per-lane weight loads, L1-cached
    int cn = cnt[i];
    for (int m = 0; m < cn; ++m) {
        int ee = ent[(size_t)m * n + i];
        int k = ee >> 24;
        int j = ee & 0xFFFFFF;
        const float4* g4 = (const float4*)(in + (size_t)j * CI);
        const float* wk = Ws + k * CI * COUT;
#pragma unroll
        for (int q = 0; q < CI / 4; ++q) {
            float4 v = g4[q];
#pragma unroll
            for (int e = 0; e < 4; ++e) {
                float fe = (e == 0) ? v.x : (e == 1) ? v.y : (e == 2) ? v.z : v.w;
                const float4* wr = (const float4*)(wk + (q * 4 + e) * COUT);
#pragma unroll
                for (int c4 = 0; c4 < COUT / 4; ++c4) {
                    float4 w = wr[c4];
                    acc[c4 * 4 + 0] += fe * w.x;
                    acc[c4 * 4 + 1] += fe * w.y;
                    acc[c4 * 4 + 2] += fe * w.z;
                    acc[c4 * 4 + 3] += fe * w.w;
                }
            }
        }
    }

#pragma unroll
    for (int c = 0; c < COUT; ++c) {
        float y = acc[c];
        acc[c] = (y >= 0.f) ? y : NEGS * y;
    }
    float4* o = (float4*)(out + (size_t)i * COUT);
#pragma unroll
    for (int c4 = 0; c4 < COUT / 4; ++c4)
        o[c4] = make_float4(acc[4 * c4 + 0], acc[4 * c4 + 1], acc[4 * c4 + 2], acc[4 * c4 + 3]);
}

__global__ __launch_bounds__(256) void add_res(float* __restrict__ out,
                                               const float* __restrict__ s, int n4) {
    int i = blockIdx.x * 256 + threadIdx.x;
    if (i < n4) {
        float4 a = ((const float4*)out)[i];
        float4 b = ((const float4*)s)[i];
        a.x += b.x; a.y += b.y; a.z += b.z; a.w += b.w;
        ((float4*)out)[i] = a;
    }
}

extern "C" void kernel_launch(void* const* d_in, const int* in_sizes, int n_in,
                              void* d_out, int out_size, void* d_ws, size_t ws_size,
                              hipStream_t stream) {
    const float* feats = (const float*)d_in[0];
    const int* coords  = (const int*)d_in[1];
    const float* W1    = (const float*)d_in[2];
    const float* W2    = (const float*)d_in[3];
    const float* W3    = (const float*)d_in[4];
    const float* W4    = (const float*)d_in[5];
    const float* gamma = (const float*)d_in[6];
    const float* beta  = (const float*)d_in[7];
    const float* mean  = (const float*)d_in[8];
    const float* var   = (const float*)d_in[9];

    int n = in_sizes[0] / CIN;  // 200000

    char* ws = (char*)d_ws;
    size_t cntBytes  = (size_t)n * sizeof(int);
    size_t entBytes  = (size_t)8 * n * sizeof(int);
    size_t wsBytes   = (size_t)27648 * sizeof(float);
    size_t shBytes   = (size_t)128 * sizeof(float);
    size_t featBytes = (size_t)n * COUT * sizeof(float);
    size_t gridBytes = (size_t)NB * DD * HH * WD * sizeof(int);

    int* cnt133 = (int*)ws;
    int* cnt313 = (int*)(ws + cntBytes);
    int* ent133 = (int*)(ws + 2 * cntBytes);
    int* ent313 = (int*)(ws + 2 * cntBytes + entBytes);
    float* Wsc  = (float*)(ws + 2 * cntBytes + 2 * entBytes);
    float* shv  = (float*)(ws + 2 * cntBytes + 2 * entBytes + wsBytes);
    char* fbase = ws + 2 * cntBytes + 2 * entBytes + wsBytes + shBytes;
    float* s1 = (float*)fbase;                      // conv1 out
    float* s2 = (float*)(fbase + featBytes);        // shortcut
    float* r1 = (float*)(fbase + 2 * featBytes);    // conv3 out
    int* grid = (int*)fbase;  // overlaps s1/s2 region; grid dead after build_nbr

    int nblk = (n + 255) / 256;

    prep_weights<<<(27648 + 255) / 256, 256, 0, stream>>>(
        W1, W2, W3, W4, gamma, beta, mean, var, Wsc, shv);
    hipMemsetAsync(grid, 0xFF, gridBytes, stream);
    scatter_grid<<<nblk, 256, 0, stream>>>(coords, grid, n);
    build_nbr_compact<<<nblk, 256, 0, stream>>>(coords, grid, cnt133, ent133,
                                                cnt313, ent313, n);

    // conv1 (feats->s1, bn0) || conv3 (feats->r1, bn2)
    conv_pair<CIN><<<2 * nblk, 256, 0, stream>>>(
        feats, cnt133, ent133, Wsc + 0,     shv + 0 * COUT, s1,
        feats, cnt313, ent313, Wsc + 13824, shv + 2 * COUT, r1,
        n, nblk);

    // conv2 (s1->s2, bn1) || conv4 (r1->d_out, bn3)
    conv_pair<COUT><<<2 * nblk, 256, 0, stream>>>(
        s1, cnt313, ent313, Wsc + 4608,  shv + 1 * COUT, s2,
        r1, cnt133, ent133, Wsc + 18432, shv + 3 * COUT, (float*)d_out,
        n, nblk);

    // d_out += s2 (resA + shortcut)
    int n4 = n * COUT / 4;
    add_res<<<(n4 + 255) / 256, 256, 0, stream>>>((float*)d_out, s2, n4);
}